// Round 2
// baseline (1178.262 us; speedup 1.0000x reference)
//
#include <hip/hip_runtime.h>
#include <hip/hip_bf16.h>

#define E_DIM 512
#define H_DIM 1024
#define V_DIM 50257
#define B_DIM 64
#define S_DIM 2048

typedef unsigned short ushort_t;
typedef __attribute__((ext_vector_type(8))) short bf16x8;
typedef __attribute__((ext_vector_type(4))) float f32x4;

__device__ __forceinline__ ushort_t f2b(float f) {
    __hip_bfloat16 h = __float2bfloat16(f);  // RNE
    ushort_t u;
    __builtin_memcpy(&u, &h, 2);
    return u;
}
__device__ __forceinline__ float dot4(float4 a, float4 b) {
    return a.x * b.x + a.y * b.y + a.z * b.z + a.w * b.w;
}

// ---------------- Kernel 1: GRU cell (f32) ----------------
// thread per (b, jh); wave lanes span b -> weight rows wave-uniform (broadcast)
__global__ __launch_bounds__(256) void k_gru(
    const float* __restrict__ x,    // [B,E]
    const float* __restrict__ h,    // [B,H]
    const float* __restrict__ w_ih, // [3H,E]
    const float* __restrict__ w_hh, // [3H,H]
    const float* __restrict__ b_ih, // [3H]
    const float* __restrict__ b_hh, // [3H]
    float* __restrict__ ws_hnew,    // [B,H]
    float* __restrict__ out_hidden) // [B,H]
{
    int g = blockIdx.x * 256 + threadIdx.x;
    int b = g & 63;
    int jh = g >> 6;
    const float4* x4 = (const float4*)(x + b * E_DIM);
    const float4* h4 = (const float4*)(h + b * H_DIM);
    const float4* wr_i = (const float4*)(w_ih + (size_t)jh * E_DIM);
    const float4* wz_i = (const float4*)(w_ih + (size_t)(jh + H_DIM) * E_DIM);
    const float4* wn_i = (const float4*)(w_ih + (size_t)(jh + 2 * H_DIM) * E_DIM);
    const float4* wr_h = (const float4*)(w_hh + (size_t)jh * H_DIM);
    const float4* wz_h = (const float4*)(w_hh + (size_t)(jh + H_DIM) * H_DIM);
    const float4* wn_h = (const float4*)(w_hh + (size_t)(jh + 2 * H_DIM) * H_DIM);

    float gir = 0.f, giz = 0.f, gin = 0.f;
    for (int e4 = 0; e4 < E_DIM / 4; ++e4) {
        float4 xv = x4[e4];
        gir += dot4(xv, wr_i[e4]);
        giz += dot4(xv, wz_i[e4]);
        gin += dot4(xv, wn_i[e4]);
    }
    float ghr = 0.f, ghz = 0.f, ghn = 0.f;
    for (int k4 = 0; k4 < H_DIM / 4; ++k4) {
        float4 hv = h4[k4];
        ghr += dot4(hv, wr_h[k4]);
        ghz += dot4(hv, wz_h[k4]);
        ghn += dot4(hv, wn_h[k4]);
    }
    gir += b_ih[jh];             ghr += b_hh[jh];
    giz += b_ih[jh + H_DIM];     ghz += b_hh[jh + H_DIM];
    gin += b_ih[jh + 2 * H_DIM]; ghn += b_hh[jh + 2 * H_DIM];

    float r = 1.f / (1.f + expf(-(gir + ghr)));
    float z = 1.f / (1.f + expf(-(giz + ghz)));
    float n = tanhf(gin + r * ghn);
    float hprev = h[b * H_DIM + jh];
    float hnew = (1.f - z) * n + z * hprev;
    ws_hnew[b * H_DIM + jh] = hnew;
    out_hidden[b * H_DIM + jh] = hnew;
}

// ---------------- Kernel 2a: energies (f32) ----------------
// wave per (b, group of 8 s); lane holds 16 h-elements
__global__ __launch_bounds__(256) void k_energy(
    const float* __restrict__ enc,  // [S,B,H]
    const float* __restrict__ hnew, // [B,H]
    float* __restrict__ energy)     // [B,S]
{
    int wave = (blockIdx.x * 256 + threadIdx.x) >> 6;
    int lane = threadIdx.x & 63;
    int b = wave >> 8;   // 256 s-groups per b
    int s8 = wave & 255;

    const float4* hv = (const float4*)(hnew + b * H_DIM + lane * 16);
    float4 h0 = hv[0], h1 = hv[1], h2 = hv[2], h3 = hv[3];

    for (int it = 0; it < 8; ++it) {
        int s = s8 * 8 + it;
        const float4* ev = (const float4*)(enc + ((size_t)s * B_DIM + b) * H_DIM + lane * 16);
        float acc = dot4(ev[0], h0) + dot4(ev[1], h1) + dot4(ev[2], h2) + dot4(ev[3], h3);
        #pragma unroll
        for (int off = 32; off; off >>= 1) acc += __shfl_xor(acc, off, 64);
        if (lane == 0) energy[b * S_DIM + s] = acc;
    }
}

// ---------------- Kernel 2b: softmax (f32) ----------------
__global__ __launch_bounds__(256) void k_softmax(
    float* __restrict__ energy,   // in: energies, out: weights [B,S]
    float* __restrict__ out_attn) // [B,1,S]
{
    int b = blockIdx.x, t = threadIdx.x;
    int lane = t & 63, wid = t >> 6;
    float e[8];
    #pragma unroll
    for (int i = 0; i < 8; ++i) e[i] = energy[b * S_DIM + i * 256 + t];
    float m = e[0];
    #pragma unroll
    for (int i = 1; i < 8; ++i) m = fmaxf(m, e[i]);
    #pragma unroll
    for (int off = 32; off; off >>= 1) m = fmaxf(m, __shfl_xor(m, off, 64));
    __shared__ float redm[4];
    __shared__ float reds[4];
    if (lane == 0) redm[wid] = m;
    __syncthreads();
    m = fmaxf(fmaxf(redm[0], redm[1]), fmaxf(redm[2], redm[3]));
    float p[8], ps = 0.f;
    #pragma unroll
    for (int i = 0; i < 8; ++i) { p[i] = expf(e[i] - m); ps += p[i]; }
    #pragma unroll
    for (int off = 32; off; off >>= 1) ps += __shfl_xor(ps, off, 64);
    if (lane == 0) reds[wid] = ps;
    __syncthreads();
    ps = reds[0] + reds[1] + reds[2] + reds[3];
    float inv = 1.f / ps;
    #pragma unroll
    for (int i = 0; i < 8; ++i) {
        float w = p[i] * inv;
        energy[b * S_DIM + i * 256 + t] = w;
        out_attn[b * S_DIM + i * 256 + t] = w;
    }
}

// ---------------- Kernel 2c: context partials (f32) ----------------
// block per (b, s-chunk of 128); thread covers 4 h; per-chunk partial vectors
__global__ __launch_bounds__(256) void k_context(
    const float* __restrict__ enc,  // [S,B,H]
    const float* __restrict__ wgt,  // [B,S]
    float* __restrict__ ctxpart)    // [B,16,H]
{
    int blk = blockIdx.x;
    int b = blk >> 4, c = blk & 15;
    int t = threadIdx.x;
    float4 a = {0.f, 0.f, 0.f, 0.f};
    for (int s = c * 128; s < c * 128 + 128; ++s) {
        float w = wgt[b * S_DIM + s];
        const float4* ev = (const float4*)(enc + ((size_t)s * B_DIM + b) * H_DIM);
        float4 v = ev[t];
        a.x += w * v.x; a.y += w * v.y; a.z += w * v.z; a.w += w * v.w;
    }
    ((float4*)(ctxpart + (size_t)(b * 16 + c) * H_DIM))[t] = a;
}

// ---------------- Kernel 2d: sum context partials ----------------
__global__ __launch_bounds__(256) void k_ctxsum(
    const float* __restrict__ ctxpart, // [B,16,H]
    float* __restrict__ ctx)           // [B,H]
{
    int g = blockIdx.x * 256 + threadIdx.x;  // B*H threads
    int b = g >> 10, hh = g & 1023;
    float acc = 0.f;
    #pragma unroll
    for (int c = 0; c < 16; ++c) acc += ctxpart[(size_t)(b * 16 + c) * H_DIM + hh];
    ctx[b * H_DIM + hh] = acc;
}

// ---------------- Kernel 3: concat projection (f32 -> bf16 X) ----------------
__global__ __launch_bounds__(256) void k_concat(
    const float* __restrict__ hnew, const float* __restrict__ ctx,
    const float* __restrict__ Wc, // [H, 2H]
    const float* __restrict__ bc, // [H]
    ushort_t* __restrict__ Xb)    // [B,H] bf16 (MFMA B-operand)
{
    int g = blockIdx.x * 256 + threadIdx.x;
    int b = g & 63, jo = g >> 6;
    const float4* w1 = (const float4*)(Wc + (size_t)jo * 2 * H_DIM);
    const float4* w2 = (const float4*)(Wc + (size_t)jo * 2 * H_DIM + H_DIM);
    const float4* hv = (const float4*)(hnew + b * H_DIM);
    const float4* cv = (const float4*)(ctx + b * H_DIM);
    float acc = bc[jo];
    for (int k4 = 0; k4 < H_DIM / 4; ++k4) {
        acc += dot4(hv[k4], w1[k4]);
        acc += dot4(cv[k4], w2[k4]);
    }
    Xb[b * H_DIM + jo] = f2b(tanhf(acc));
}

// ---------------- Kernel 4: vocab projection (MFMA, f32 W_out cast inline) ----------------
// wave computes 16 v x 64 b; A = W_out rows (v, cvt f32->bf16 in-register), B = Xb rows
__global__ __launch_bounds__(256) void k_out(
    const float* __restrict__ Wout,  // [V,H] f32
    const ushort_t* __restrict__ Xb, // [B,H] bf16
    const float* __restrict__ bout,  // [V] f32
    float* __restrict__ out)         // [B,V] f32
{
    int wave = (blockIdx.x * 256 + threadIdx.x) >> 6;
    int lane = threadIdx.x & 63;
    int v0 = wave * 16;
    if (v0 >= V_DIM) return;
    int m = lane & 15, quad = lane >> 4;
    int arow = v0 + m;
    if (arow > V_DIM - 1) arow = V_DIM - 1;
    const float* wr = Wout + (size_t)arow * H_DIM + quad * 8;
    const short* xrow = (const short*)Xb + m * H_DIM + quad * 8;

    f32x4 acc[4] = {{0.f, 0.f, 0.f, 0.f}, {0.f, 0.f, 0.f, 0.f},
                    {0.f, 0.f, 0.f, 0.f}, {0.f, 0.f, 0.f, 0.f}};
    for (int k0 = 0; k0 < H_DIM; k0 += 32) {
        float4 a0 = *(const float4*)(wr + k0);
        float4 a1 = *(const float4*)(wr + k0 + 4);
        bf16x8 a;
        a[0] = (short)f2b(a0.x); a[1] = (short)f2b(a0.y);
        a[2] = (short)f2b(a0.z); a[3] = (short)f2b(a0.w);
        a[4] = (short)f2b(a1.x); a[5] = (short)f2b(a1.y);
        a[6] = (short)f2b(a1.z); a[7] = (short)f2b(a1.w);
        #pragma unroll
        for (int bt = 0; bt < 4; ++bt) {
            bf16x8 bb = *(const bf16x8*)(xrow + bt * 16 * H_DIM + k0);
            acc[bt] = __builtin_amdgcn_mfma_f32_16x16x32_bf16(a, bb, acc[bt], 0, 0, 0);
        }
    }
    // C/D layout (m89-verified): col(n=b-local)=lane&15, row(m=v-local)=quad*4+reg
    #pragma unroll
    for (int bt = 0; bt < 4; ++bt) {
        int b = bt * 16 + m;
        #pragma unroll
        for (int r = 0; r < 4; ++r) {
            int v = v0 + quad * 4 + r;
            if (v < V_DIM) out[(size_t)b * V_DIM + v] = acc[bt][r] + bout[v];
        }
    }
}

extern "C" void kernel_launch(void* const* d_in, const int* in_sizes, int n_in,
                              void* d_out, int out_size, void* d_ws, size_t ws_size,
                              hipStream_t stream) {
    const float* x    = (const float*)d_in[0];
    const float* h    = (const float*)d_in[1];
    const float* enc  = (const float*)d_in[2];
    const float* w_ih = (const float*)d_in[3];
    const float* w_hh = (const float*)d_in[4];
    const float* b_ih = (const float*)d_in[5];
    const float* b_hh = (const float*)d_in[6];
    const float* Wc   = (const float*)d_in[7];
    const float* bc   = (const float*)d_in[8];
    const float* Wout = (const float*)d_in[9];
    const float* bout = (const float*)d_in[10];

    float* out        = (float*)d_out;
    float* out_hidden = out + (size_t)B_DIM * V_DIM;
    float* out_attn   = out_hidden + B_DIM * H_DIM;

    // ws layout (needs 5.125 MB):
    char* ws = (char*)d_ws;
    float* ws_hnew    = (float*)ws;                      // 256 KB [B,H]
    float* ws_energy  = (float*)(ws + (256 << 10));      // 512 KB [B,S]
    float* ws_ctx     = (float*)(ws + (768 << 10));      // 256 KB [B,H]
    ushort_t* ws_Xb   = (ushort_t*)(ws + (1024 << 10));  // 128 KB [B,H] bf16
    float* ws_ctxpart = (float*)(ws + (1152 << 10));     // 4 MB [B,16,H]

    k_gru<<<B_DIM * H_DIM / 256, 256, 0, stream>>>(x, h, w_ih, w_hh, b_ih, b_hh,
                                                   ws_hnew, out_hidden);
    k_energy<<<B_DIM * S_DIM / 8 / 4, 256, 0, stream>>>(enc, ws_hnew, ws_energy);
    k_softmax<<<B_DIM, 256, 0, stream>>>(ws_energy, out_attn);
    k_context<<<B_DIM * 16, 256, 0, stream>>>(enc, ws_energy, ws_ctxpart);
    k_ctxsum<<<B_DIM * H_DIM / 256, 256, 0, stream>>>(ws_ctxpart, ws_ctx);
    k_concat<<<B_DIM * H_DIM / 256, 256, 0, stream>>>(ws_hnew, ws_ctx, Wc, bc, ws_Xb);
    int waves4 = (V_DIM + 15) / 16;
    k_out<<<(waves4 + 3) / 4, 256, 0, stream>>>(Wout, ws_Xb, bout, out);
}